// Round 7
// baseline (308.070 us; speedup 1.0000x reference)
//
#include <hip/hip_runtime.h>
#include <cmath>

#define NN 50000
#define KK 15
#define DD 128
#define HH 64
#define NKE (NN * KK)

#define TP_ROWS 64
#define TP_STRIDE 129   // odd dword stride: LDS bank = (lane + k) % 32 -> max 2-way (free)

// ---------------------------------------------------------------------------
// kP (R6 version, kept): LDS-staged row-per-lane GEMM, k-loop chunks of 8.
// R5->R6: chunked unroll made 8 ds_reads + weight s_loads co-outstanding,
// kP dropped below the 91.5 us top-5 cutoff (was 98).  Weights WAVE-UNIFORM
// (s_load path; session invariant).  R1 lesson: no global->reg ping-pong.
// ---------------------------------------------------------------------------
__global__ __launch_bounds__(384, 2) void kP(const float* __restrict__ x,
                                             const float* __restrict__ ew1,
                                             const float* __restrict__ dw1,
                                             float* __restrict__ ws) {
    __shared__ float xt[TP_ROWS * TP_STRIDE];   // 33,024 B
    int t = threadIdx.x;
    int lane = t & 63;
    int w = __builtin_amdgcn_readfirstlane(t >> 6);   // 0..5
    int seg = w >> 1;            // 0..2  (XA, XB, XC)
    int jh  = w & 1;             // 0..1  (j-half)
    int row0 = blockIdx.x * TP_ROWS;

    // ---- stage x tile: coalesced float4 global loads, b32 LDS writes ----
    for (int i = t; i < TP_ROWS * DD / 4; i += 384) {
        int r = (i * 4) / DD;
        int c = (i * 4) % DD;
        float4 v = make_float4(0.f, 0.f, 0.f, 0.f);
        if (row0 + r < NN) v = *(const float4*)(x + (size_t)(row0 + r) * DD + c);
        float* p = &xt[r * TP_STRIDE + c];
        p[0] = v.x; p[1] = v.y; p[2] = v.z; p[3] = v.w;
    }
    __syncthreads();

    // wave-uniform weight base: virtual row k lives at Wb + k*HH (+ jh*32)
    const float* Wb = (seg == 0) ? (ew1 + jh * 32)
                    : (seg == 1) ? (ew1 + (size_t)DD * HH + jh * 32)
                                 : (dw1 + jh * 32);

    float acc[32];
#pragma unroll
    for (int j = 0; j < 32; ++j) acc[j] = 0.f;

    const float* xrow = &xt[lane * TP_STRIDE];
#pragma unroll 1
    for (int kc = 0; kc < DD; kc += 8) {
        float xv[8];
#pragma unroll
        for (int u = 0; u < 8; ++u) xv[u] = xrow[kc + u];
#pragma unroll
        for (int u = 0; u < 8; ++u) {
            const float* wr = Wb + (size_t)(kc + u) * HH;   // wave-uniform
#pragma unroll
            for (int j4 = 0; j4 < 8; ++j4) {
                float4 wv = *(const float4*)(wr + j4 * 4);
                acc[j4 * 4 + 0] = fmaf(xv[u], wv.x, acc[j4 * 4 + 0]);
                acc[j4 * 4 + 1] = fmaf(xv[u], wv.y, acc[j4 * 4 + 1]);
                acc[j4 * 4 + 2] = fmaf(xv[u], wv.z, acc[j4 * 4 + 2]);
                acc[j4 * 4 + 3] = fmaf(xv[u], wv.w, acc[j4 * 4 + 3]);
            }
        }
    }

    int myrow = row0 + lane;
    if (myrow < NN) {
        float* o = ws + (size_t)seg * NN * HH + (size_t)myrow * HH + jh * 32;
#pragma unroll
        for (int j4 = 0; j4 < 8; ++j4)
            *(float4*)(o + j4 * 4) = make_float4(acc[j4 * 4 + 0], acc[j4 * 4 + 1],
                                                 acc[j4 * 4 + 2], acc[j4 * 4 + 3]);
    }
}

// ---------------------------------------------------------------------------
// kE: thread-per-edge (EXACT R0 version — 92-93 us anchor, VALUBusy 58%).
// acc[64] AGPR-backed, ew2 rows WAVE-UNIFORM -> s_load scalar path.
// Falsified alternatives: lane-split j (R1/R2: per-lane VMEM weights, 8%
// VALUBusy), wave-split j (R4: occupancy 68% but 117 us — VALU work
// constant, same s_load stall pattern in every wave).
// ---------------------------------------------------------------------------
__global__ __launch_bounds__(128, 4) void kE(const int* __restrict__ srcIdx,
                                             const float* __restrict__ dist,
                                             const float* __restrict__ ws,
                                             const float* __restrict__ ew1,
                                             const float* __restrict__ eb1,
                                             const float* __restrict__ ew2,
                                             const float* __restrict__ eb2,
                                             const float* __restrict__ ew3,
                                             const float* __restrict__ eb3,
                                             float* __restrict__ energy_out) {
    int e = blockIdx.x * 128 + threadIdx.x;
    if (e >= NKE) return;
    int s = srcIdx[e];
    int d = e / KK;
    float dd = dist[e];
    const float* A = ws + (size_t)d * HH;
    const float* B = ws + (size_t)NN * HH + (size_t)s * HH;
    const float* w1l = ew1 + 2 * DD * HH;

    float acc[HH];
#pragma unroll
    for (int j = 0; j < HH; ++j) acc[j] = 0.f;

    float4 a4 = *(const float4*)A;
    float4 b4 = *(const float4*)B;
#pragma unroll 1
    for (int i4 = 0; i4 < HH / 4; ++i4) {
        float4 a = a4, b = b4;
        int nx = (i4 + 1 < HH / 4) ? (i4 + 1) : i4;
        a4 = *(const float4*)(A + nx * 4);
        b4 = *(const float4*)(B + nx * 4);
        float h[4];
        h[0] = fmaxf(a.x + b.x + dd * w1l[i4 * 4 + 0] + eb1[i4 * 4 + 0], 0.f);
        h[1] = fmaxf(a.y + b.y + dd * w1l[i4 * 4 + 1] + eb1[i4 * 4 + 1], 0.f);
        h[2] = fmaxf(a.z + b.z + dd * w1l[i4 * 4 + 2] + eb1[i4 * 4 + 2], 0.f);
        h[3] = fmaxf(a.w + b.w + dd * w1l[i4 * 4 + 3] + eb1[i4 * 4 + 3], 0.f);
#pragma unroll
        for (int k = 0; k < 4; ++k) {
            const float* wr = ew2 + (i4 * 4 + k) * HH;   // wave-uniform!
#pragma unroll
            for (int j4 = 0; j4 < 16; ++j4) {
                float4 w = *(const float4*)(wr + j4 * 4);
                acc[j4 * 4 + 0] = fmaf(h[k], w.x, acc[j4 * 4 + 0]);
                acc[j4 * 4 + 1] = fmaf(h[k], w.y, acc[j4 * 4 + 1]);
                acc[j4 * 4 + 2] = fmaf(h[k], w.z, acc[j4 * 4 + 2]);
                acc[j4 * 4 + 3] = fmaf(h[k], w.w, acc[j4 * 4 + 3]);
            }
        }
    }
    float lg = eb3[0];
#pragma unroll
    for (int j = 0; j < HH; ++j)
        lg = fmaf(fmaxf(acc[j] + eb2[j], 0.f), ew3[j], lg);
    energy_out[e] = 1.f / (1.f + expf(-2.f * lg));
}

// ---------------------------------------------------------------------------
// kF: thread-per-node (EXACT R0 version — the only kF tied to the 269.8 us
// best-known total; R3 lane-split = 103 us measured; R4 wave-split is
// un-attributable, totals suggest it may be ~100 us not ~64).
// ---------------------------------------------------------------------------
__global__ __launch_bounds__(128, 4) void kF(const float* __restrict__ ws,
                                             const float* __restrict__ dw1,
                                             const float* __restrict__ db1,
                                             const float* __restrict__ dw2,
                                             const float* __restrict__ db2,
                                             const float* __restrict__ dw3,
                                             const float* __restrict__ db3,
                                             float* __restrict__ out) {
    int n = blockIdx.x * 128 + threadIdx.x;
    if (n >= NN) return;
    const float* energy = out + 2 * (size_t)NKE;

    float ev[KK];
    float dh = 0.f;
#pragma unroll
    for (int j = 0; j < KK; ++j) {
        ev[j] = energy[(size_t)n * KK + j];
        dh += ev[j];
    }

    const float* XC = ws + 2 * (size_t)NN * HH + (size_t)n * HH;
    const float* w1l = dw1 + DD * HH;

    float acc[HH];
#pragma unroll
    for (int j = 0; j < HH; ++j) acc[j] = 0.f;

    float4 c4 = *(const float4*)XC;
#pragma unroll 1
    for (int i4 = 0; i4 < HH / 4; ++i4) {
        float4 c = c4;
        int nx = (i4 + 1 < HH / 4) ? (i4 + 1) : i4;
        c4 = *(const float4*)(XC + nx * 4);
        float cv[4] = {c.x, c.y, c.z, c.w};
#pragma unroll
        for (int m = 0; m < 4; ++m) {
            int k = i4 * 4 + m;
            float g = fmaxf(cv[m] + dh * w1l[k] + db1[k], 0.f);
            const float* wr = dw2 + k * HH;            // wave-uniform
#pragma unroll
            for (int j4 = 0; j4 < 16; ++j4) {
                float4 w = *(const float4*)(wr + j4 * 4);
                acc[j4 * 4 + 0] = fmaf(g, w.x, acc[j4 * 4 + 0]);
                acc[j4 * 4 + 1] = fmaf(g, w.y, acc[j4 * 4 + 1]);
                acc[j4 * 4 + 2] = fmaf(g, w.z, acc[j4 * 4 + 2]);
                acc[j4 * 4 + 3] = fmaf(g, w.w, acc[j4 * 4 + 3]);
            }
        }
    }
    float kraw = db3[0];
#pragma unroll
    for (int j = 0; j < HH; ++j)
        kraw = fmaf(fmaxf(acc[j] + db2[j], 0.f), dw3[j], kraw);

    float kcont = 2.f + 13.f / (1.f + expf(-kraw));
    out[3 * (size_t)NKE + n] = kcont;

    // register-resident sort of (energy desc, idx asc), 16-wide network
    float se[16];
    int si[16];
#pragma unroll
    for (int j = 0; j < KK; ++j) { se[j] = ev[j]; si[j] = j; }
    se[15] = -1.f; si[15] = 15;

#pragma unroll
    for (int p = 1; p < 16; p <<= 1) {
#pragma unroll
        for (int k = p; k >= 1; k >>= 1) {
#pragma unroll
            for (int j = k & (p - 1); j + k < 16; j += 2 * k) {
#pragma unroll
                for (int i = 0; i < k; ++i) {
                    int a = i + j, b = i + j + k;
                    if (b < 16 && (a / (2 * p)) == (b / (2 * p))) {
                        bool sw = (se[b] > se[a]) ||
                                  (se[b] == se[a] && si[b] < si[a]);
                        float ea = sw ? se[b] : se[a];
                        float eb = sw ? se[a] : se[b];
                        int ia = sw ? si[b] : si[a];
                        int ib = sw ? si[a] : si[b];
                        se[a] = ea; se[b] = eb; si[a] = ia; si[b] = ib;
                    }
                }
            }
        }
    }

    float kint = rintf(kcont);
    kint = fminf(fmaxf(kint, 2.f), 15.f);

    float wsrt[KK];
    float denom = 0.f;
#pragma unroll
    for (int r = 0; r < KK; ++r) {
        float sel = ((float)(r + 1) <= kint) ? 1.f : 0.f;
        float wvv = se[r] * sel;
        wsrt[r] = wvv;
        denom += wvv;
    }
    denom = fmaxf(denom, 1e-12f);

#pragma unroll
    for (int r = 0; r < KK; ++r) {
        float sel = ((float)(r + 1) <= kint) ? 1.f : 0.f;
        int j0 = si[r];
        out[(size_t)NKE + (size_t)n * KK + j0] = sel;     // edge_gate
        out[(size_t)n * KK + j0] = wsrt[r] / denom;       // edge_weight
    }
}

extern "C" void kernel_launch(void* const* d_in, const int* in_sizes, int n_in,
                              void* d_out, int out_size, void* d_ws, size_t ws_size,
                              hipStream_t stream) {
    const float* x   = (const float*)d_in[0];
    const int*   ei  = (const int*)d_in[1];
    const float* ed  = (const float*)d_in[2];
    const float* ew1 = (const float*)d_in[3];
    const float* eb1 = (const float*)d_in[4];
    const float* ew2 = (const float*)d_in[5];
    const float* eb2 = (const float*)d_in[6];
    const float* ew3 = (const float*)d_in[7];
    const float* eb3 = (const float*)d_in[8];
    const float* dw1 = (const float*)d_in[9];
    const float* db1 = (const float*)d_in[10];
    const float* dw2 = (const float*)d_in[11];
    const float* db2 = (const float*)d_in[12];
    const float* dw3 = (const float*)d_in[13];
    const float* db3 = (const float*)d_in[14];
    float* out = (float*)d_out;
    float* ws  = (float*)d_ws;

    hipLaunchKernelGGL(kP, dim3((NN + TP_ROWS - 1) / TP_ROWS), dim3(384), 0, stream,
                       x, ew1, dw1, ws);
    hipLaunchKernelGGL(kE, dim3((NKE + 127) / 128), dim3(128), 0, stream,
                       ei, ed, ws, ew1, eb1, ew2, eb2, ew3, eb3,
                       out + 2 * (size_t)NKE);
    hipLaunchKernelGGL(kF, dim3((NN + 127) / 128), dim3(128), 0, stream,
                       ws, dw1, db1, dw2, db2, dw3, db3, out);
}

// Round 8
// 272.917 us; speedup vs baseline: 1.1288x; 1.1288x over previous
//
#include <hip/hip_runtime.h>
#include <cmath>

#define NN 50000
#define KK 15
#define DD 128
#define HH 64
#define NKE (NN * KK)

// ---------------------------------------------------------------------------
// kP: fused 3-segment per-node GEMM, NO LDS.  (EXACT R0 version.)
// R7 ledger-refit: this version is ~65-70 us; the R5/R6 LDS-staged rewrite
// was 85-100 us (regression) — reverted.  x read with wave-uniform scalar
// addresses; weights lane-coalesced VMEM; 12 FMAs per x float4.
// R1 lesson: no register ping-pong buffers (spill storm, 41 ms).
// ---------------------------------------------------------------------------
__global__ __launch_bounds__(256) void kP(const float* __restrict__ x,
                                          const float* __restrict__ ew1,
                                          const float* __restrict__ dw1,
                                          float* __restrict__ ws) {
    int lane = threadIdx.x & 63;
    int wv = __builtin_amdgcn_readfirstlane((int)(threadIdx.x >> 6));
    int r0 = blockIdx.x * 32 + wv * 8;       // 50000 % 8 == 0: no intra-wave tail
    if (r0 >= NN) return;

    const float* W0 = ew1;
    const float* W1 = ew1 + DD * HH;
    const float* W2 = dw1;
    const float* xw = x + (size_t)r0 * DD;

    float a0[8], a1[8], a2[8];
#pragma unroll
    for (int r = 0; r < 8; ++r) { a0[r] = 0.f; a1[r] = 0.f; a2[r] = 0.f; }

#pragma unroll 1
    for (int i4 = 0; i4 < DD / 4; ++i4) {
        float w00 = W0[(i4 * 4 + 0) * HH + lane];
        float w01 = W0[(i4 * 4 + 1) * HH + lane];
        float w02 = W0[(i4 * 4 + 2) * HH + lane];
        float w03 = W0[(i4 * 4 + 3) * HH + lane];
        float w10 = W1[(i4 * 4 + 0) * HH + lane];
        float w11 = W1[(i4 * 4 + 1) * HH + lane];
        float w12 = W1[(i4 * 4 + 2) * HH + lane];
        float w13 = W1[(i4 * 4 + 3) * HH + lane];
        float w20 = W2[(i4 * 4 + 0) * HH + lane];
        float w21 = W2[(i4 * 4 + 1) * HH + lane];
        float w22 = W2[(i4 * 4 + 2) * HH + lane];
        float w23 = W2[(i4 * 4 + 3) * HH + lane];
#pragma unroll
        for (int r = 0; r < 8; ++r) {
            // wave-uniform address -> scalar broadcast, no LDS
            float4 xv = *(const float4*)(xw + r * DD + i4 * 4);
            a0[r] = fmaf(xv.x, w00, a0[r]);
            a0[r] = fmaf(xv.y, w01, a0[r]);
            a0[r] = fmaf(xv.z, w02, a0[r]);
            a0[r] = fmaf(xv.w, w03, a0[r]);
            a1[r] = fmaf(xv.x, w10, a1[r]);
            a1[r] = fmaf(xv.y, w11, a1[r]);
            a1[r] = fmaf(xv.z, w12, a1[r]);
            a1[r] = fmaf(xv.w, w13, a1[r]);
            a2[r] = fmaf(xv.x, w20, a2[r]);
            a2[r] = fmaf(xv.y, w21, a2[r]);
            a2[r] = fmaf(xv.z, w22, a2[r]);
            a2[r] = fmaf(xv.w, w23, a2[r]);
        }
    }
    float* o0 = ws + (size_t)r0 * HH + lane;
    float* o1 = ws + (size_t)NN * HH + (size_t)r0 * HH + lane;
    float* o2 = ws + 2 * (size_t)NN * HH + (size_t)r0 * HH + lane;
#pragma unroll
    for (int r = 0; r < 8; ++r) {
        o0[r * HH] = a0[r];
        o1[r * HH] = a1[r];
        o2[r * HH] = a2[r];
    }
}

// ---------------------------------------------------------------------------
// kE (R8): TWO EDGES PER THREAD.  93 us / VALUBusy 58% at R0; floor is
// ~41 us of pure FMA.  The stall budget (ew2 s_load waits + A/B gather
// waits) is amortized: each wave-uniform ew2 float4 now feeds 8 FMAs
// (2 edges x 4) instead of 4; 4 independent gathers in flight instead of 2.
// acc[2][64] = 128 AGPR-backed + ~60 arch VGPR ~= 190 < 256 cap at (128,2)
// -> no spill (R1's failure was cap 84 < need 90; here headroom is 1.3x).
// Weights remain WAVE-UNIFORM (session invariant, falsified twice otherwise).
// ---------------------------------------------------------------------------
__global__ __launch_bounds__(128, 2) void kE(const int* __restrict__ srcIdx,
                                             const float* __restrict__ dist,
                                             const float* __restrict__ ws,
                                             const float* __restrict__ ew1,
                                             const float* __restrict__ eb1,
                                             const float* __restrict__ ew2,
                                             const float* __restrict__ eb2,
                                             const float* __restrict__ ew3,
                                             const float* __restrict__ eb3,
                                             float* __restrict__ energy_out) {
    int t = blockIdx.x * 128 + threadIdx.x;
    if (t >= NKE / 2) return;
    int e0 = 2 * t;
    int e1 = e0 + 1;                           // NKE even: always valid

    int s0 = srcIdx[e0], s1 = srcIdx[e1];
    int d0 = e0 / KK,    d1 = e1 / KK;
    float dd0 = dist[e0], dd1 = dist[e1];
    const float* A0 = ws + (size_t)d0 * HH;
    const float* B0 = ws + (size_t)NN * HH + (size_t)s0 * HH;
    const float* A1 = ws + (size_t)d1 * HH;
    const float* B1 = ws + (size_t)NN * HH + (size_t)s1 * HH;
    const float* w1l = ew1 + 2 * DD * HH;

    float acc0[HH], acc1[HH];
#pragma unroll
    for (int j = 0; j < HH; ++j) { acc0[j] = 0.f; acc1[j] = 0.f; }

    float4 a04 = *(const float4*)A0;
    float4 b04 = *(const float4*)B0;
    float4 a14 = *(const float4*)A1;
    float4 b14 = *(const float4*)B1;
#pragma unroll 1
    for (int i4 = 0; i4 < HH / 4; ++i4) {
        float4 a0v = a04, b0v = b04, a1v = a14, b1v = b14;
        int nx = (i4 + 1 < HH / 4) ? (i4 + 1) : i4;
        a04 = *(const float4*)(A0 + nx * 4);
        b04 = *(const float4*)(B0 + nx * 4);
        a14 = *(const float4*)(A1 + nx * 4);
        b14 = *(const float4*)(B1 + nx * 4);
        float h0[4], h1[4];
        h0[0] = fmaxf(a0v.x + b0v.x + dd0 * w1l[i4 * 4 + 0] + eb1[i4 * 4 + 0], 0.f);
        h0[1] = fmaxf(a0v.y + b0v.y + dd0 * w1l[i4 * 4 + 1] + eb1[i4 * 4 + 1], 0.f);
        h0[2] = fmaxf(a0v.z + b0v.z + dd0 * w1l[i4 * 4 + 2] + eb1[i4 * 4 + 2], 0.f);
        h0[3] = fmaxf(a0v.w + b0v.w + dd0 * w1l[i4 * 4 + 3] + eb1[i4 * 4 + 3], 0.f);
        h1[0] = fmaxf(a1v.x + b1v.x + dd1 * w1l[i4 * 4 + 0] + eb1[i4 * 4 + 0], 0.f);
        h1[1] = fmaxf(a1v.y + b1v.y + dd1 * w1l[i4 * 4 + 1] + eb1[i4 * 4 + 1], 0.f);
        h1[2] = fmaxf(a1v.z + b1v.z + dd1 * w1l[i4 * 4 + 2] + eb1[i4 * 4 + 2], 0.f);
        h1[3] = fmaxf(a1v.w + b1v.w + dd1 * w1l[i4 * 4 + 3] + eb1[i4 * 4 + 3], 0.f);
#pragma unroll
        for (int k = 0; k < 4; ++k) {
            const float* wr = ew2 + (i4 * 4 + k) * HH;   // wave-uniform s_load
#pragma unroll
            for (int j4 = 0; j4 < 16; ++j4) {
                float4 w = *(const float4*)(wr + j4 * 4); // 1 s_load -> 8 FMAs
                acc0[j4 * 4 + 0] = fmaf(h0[k], w.x, acc0[j4 * 4 + 0]);
                acc0[j4 * 4 + 1] = fmaf(h0[k], w.y, acc0[j4 * 4 + 1]);
                acc0[j4 * 4 + 2] = fmaf(h0[k], w.z, acc0[j4 * 4 + 2]);
                acc0[j4 * 4 + 3] = fmaf(h0[k], w.w, acc0[j4 * 4 + 3]);
                acc1[j4 * 4 + 0] = fmaf(h1[k], w.x, acc1[j4 * 4 + 0]);
                acc1[j4 * 4 + 1] = fmaf(h1[k], w.y, acc1[j4 * 4 + 1]);
                acc1[j4 * 4 + 2] = fmaf(h1[k], w.z, acc1[j4 * 4 + 2]);
                acc1[j4 * 4 + 3] = fmaf(h1[k], w.w, acc1[j4 * 4 + 3]);
            }
        }
    }
    float lg0 = eb3[0], lg1 = eb3[0];
#pragma unroll
    for (int j = 0; j < HH; ++j) {
        float w3 = ew3[j], b2 = eb2[j];
        lg0 = fmaf(fmaxf(acc0[j] + b2, 0.f), w3, lg0);
        lg1 = fmaf(fmaxf(acc1[j] + b2, 0.f), w3, lg1);
    }
    energy_out[e0] = 1.f / (1.f + expf(-2.f * lg0));
    energy_out[e1] = 1.f / (1.f + expf(-2.f * lg1));
}

// ---------------------------------------------------------------------------
// kF: thread-per-node (EXACT R0 version — part of the 269.8 us best total).
// R3 lane-split measured 103 us; R4 wave-split ~= this per the R7 ledger
// refit; keep the simplest proven form.
// ---------------------------------------------------------------------------
__global__ __launch_bounds__(128, 4) void kF(const float* __restrict__ ws,
                                             const float* __restrict__ dw1,
                                             const float* __restrict__ db1,
                                             const float* __restrict__ dw2,
                                             const float* __restrict__ db2,
                                             const float* __restrict__ dw3,
                                             const float* __restrict__ db3,
                                             float* __restrict__ out) {
    int n = blockIdx.x * 128 + threadIdx.x;
    if (n >= NN) return;
    const float* energy = out + 2 * (size_t)NKE;

    float ev[KK];
    float dh = 0.f;
#pragma unroll
    for (int j = 0; j < KK; ++j) {
        ev[j] = energy[(size_t)n * KK + j];
        dh += ev[j];
    }

    const float* XC = ws + 2 * (size_t)NN * HH + (size_t)n * HH;
    const float* w1l = dw1 + DD * HH;

    float acc[HH];
#pragma unroll
    for (int j = 0; j < HH; ++j) acc[j] = 0.f;

    float4 c4 = *(const float4*)XC;
#pragma unroll 1
    for (int i4 = 0; i4 < HH / 4; ++i4) {
        float4 c = c4;
        int nx = (i4 + 1 < HH / 4) ? (i4 + 1) : i4;
        c4 = *(const float4*)(XC + nx * 4);
        float cv[4] = {c.x, c.y, c.z, c.w};
#pragma unroll
        for (int m = 0; m < 4; ++m) {
            int k = i4 * 4 + m;
            float g = fmaxf(cv[m] + dh * w1l[k] + db1[k], 0.f);
            const float* wr = dw2 + k * HH;            // wave-uniform
#pragma unroll
            for (int j4 = 0; j4 < 16; ++j4) {
                float4 w = *(const float4*)(wr + j4 * 4);
                acc[j4 * 4 + 0] = fmaf(g, w.x, acc[j4 * 4 + 0]);
                acc[j4 * 4 + 1] = fmaf(g, w.y, acc[j4 * 4 + 1]);
                acc[j4 * 4 + 2] = fmaf(g, w.z, acc[j4 * 4 + 2]);
                acc[j4 * 4 + 3] = fmaf(g, w.w, acc[j4 * 4 + 3]);
            }
        }
    }
    float kraw = db3[0];
#pragma unroll
    for (int j = 0; j < HH; ++j)
        kraw = fmaf(fmaxf(acc[j] + db2[j], 0.f), dw3[j], kraw);

    float kcont = 2.f + 13.f / (1.f + expf(-kraw));
    out[3 * (size_t)NKE + n] = kcont;

    // register-resident sort of (energy desc, idx asc), 16-wide network
    float se[16];
    int si[16];
#pragma unroll
    for (int j = 0; j < KK; ++j) { se[j] = ev[j]; si[j] = j; }
    se[15] = -1.f; si[15] = 15;

#pragma unroll
    for (int p = 1; p < 16; p <<= 1) {
#pragma unroll
        for (int k = p; k >= 1; k >>= 1) {
#pragma unroll
            for (int j = k & (p - 1); j + k < 16; j += 2 * k) {
#pragma unroll
                for (int i = 0; i < k; ++i) {
                    int a = i + j, b = i + j + k;
                    if (b < 16 && (a / (2 * p)) == (b / (2 * p))) {
                        bool sw = (se[b] > se[a]) ||
                                  (se[b] == se[a] && si[b] < si[a]);
                        float ea = sw ? se[b] : se[a];
                        float eb = sw ? se[a] : se[b];
                        int ia = sw ? si[b] : si[a];
                        int ib = sw ? si[a] : si[b];
                        se[a] = ea; se[b] = eb; si[a] = ia; si[b] = ib;
                    }
                }
            }
        }
    }

    float kint = rintf(kcont);
    kint = fminf(fmaxf(kint, 2.f), 15.f);

    float wsrt[KK];
    float denom = 0.f;
#pragma unroll
    for (int r = 0; r < KK; ++r) {
        float sel = ((float)(r + 1) <= kint) ? 1.f : 0.f;
        float wvv = se[r] * sel;
        wsrt[r] = wvv;
        denom += wvv;
    }
    denom = fmaxf(denom, 1e-12f);

#pragma unroll
    for (int r = 0; r < KK; ++r) {
        float sel = ((float)(r + 1) <= kint) ? 1.f : 0.f;
        int j0 = si[r];
        out[(size_t)NKE + (size_t)n * KK + j0] = sel;     // edge_gate
        out[(size_t)n * KK + j0] = wsrt[r] / denom;       // edge_weight
    }
}

extern "C" void kernel_launch(void* const* d_in, const int* in_sizes, int n_in,
                              void* d_out, int out_size, void* d_ws, size_t ws_size,
                              hipStream_t stream) {
    const float* x   = (const float*)d_in[0];
    const int*   ei  = (const int*)d_in[1];
    const float* ed  = (const float*)d_in[2];
    const float* ew1 = (const float*)d_in[3];
    const float* eb1 = (const float*)d_in[4];
    const float* ew2 = (const float*)d_in[5];
    const float* eb2 = (const float*)d_in[6];
    const float* ew3 = (const float*)d_in[7];
    const float* eb3 = (const float*)d_in[8];
    const float* dw1 = (const float*)d_in[9];
    const float* db1 = (const float*)d_in[10];
    const float* dw2 = (const float*)d_in[11];
    const float* db2 = (const float*)d_in[12];
    const float* dw3 = (const float*)d_in[13];
    const float* db3 = (const float*)d_in[14];
    float* out = (float*)d_out;
    float* ws  = (float*)d_ws;

    hipLaunchKernelGGL(kP, dim3((NN + 31) / 32), dim3(256), 0, stream,
                       x, ew1, dw1, ws);
    hipLaunchKernelGGL(kE, dim3((NKE / 2 + 127) / 128), dim3(128), 0, stream,
                       ei, ed, ws, ew1, eb1, ew2, eb2, ew3, eb3,
                       out + 2 * (size_t)NKE);
    hipLaunchKernelGGL(kF, dim3((NN + 127) / 128), dim3(128), 0, stream,
                       ws, dw1, db1, dw2, db2, dw3, db3, out);
}